// Round 1
// baseline (344.172 us; speedup 1.0000x reference)
//
#include <hip/hip_runtime.h>
#include <hip/hip_bf16.h>

#define C 128
#define L 16384
#define B 8
#define MID 32
#define NBL (B * L)

typedef unsigned short ushort_t;
typedef __attribute__((ext_vector_type(8))) short s8v;   // 8 bf16
typedef __attribute__((ext_vector_type(4))) float f4v;   // 4 fp32

__device__ __forceinline__ unsigned short f2bf(float f) {
    union { float f; unsigned int u; } a; a.f = f;
    unsigned int u = a.u;
    return (unsigned short)((u + 0x7fffu + ((u >> 16) & 1u)) >> 16);
}

__device__ __forceinline__ void load8(const ushort_t* p, float* f) {
    uint4 u = *(const uint4*)p;
    f[0] = __uint_as_float(u.x << 16); f[1] = __uint_as_float(u.x & 0xffff0000u);
    f[2] = __uint_as_float(u.y << 16); f[3] = __uint_as_float(u.y & 0xffff0000u);
    f[4] = __uint_as_float(u.z << 16); f[5] = __uint_as_float(u.z & 0xffff0000u);
    f[6] = __uint_as_float(u.w << 16); f[7] = __uint_as_float(u.w & 0xffff0000u);
}

__device__ __forceinline__ void zero8(float* f) {
#pragma unroll
    for (int j = 0; j < 8; j++) f[j] = 0.f;
}

__device__ __forceinline__ void ld8f(const float* p, float* f) {
    float4 a = *(const float4*)p;
    float4 b = *(const float4*)(p + 4);
    f[0] = a.x; f[1] = a.y; f[2] = a.z; f[3] = a.w;
    f[4] = b.x; f[5] = b.y; f[6] = b.z; f[7] = b.w;
}

// ------------------------------------------------ k_cvt: x fp32 [b][c][l] -> xb_t bf16 [b][l][c], + gap sums
__global__ __launch_bounds__(256) void k_cvt(const float* __restrict__ x,
                                             ushort_t* __restrict__ xb,
                                             float* __restrict__ gap) {
    __shared__ float xs[64][129];
    const int bid = blockIdx.x;
    const int b = bid >> 8;
    const int l0 = (bid & 255) * 64;
    const int tid = threadIdx.x;
    const int c = tid >> 1, h = tid & 1;
    const float* src = x + ((size_t)(b * C + c)) * L + l0 + h * 32;
    float s = 0.f;
#pragma unroll
    for (int j = 0; j < 8; j++) {
        float4 v = *(const float4*)(src + j * 4);
        s += (v.x + v.y) + (v.z + v.w);
        int lb = h * 32 + j * 4;
        xs[lb + 0][c] = v.x; xs[lb + 1][c] = v.y;
        xs[lb + 2][c] = v.z; xs[lb + 3][c] = v.w;
    }
    s += __shfl_xor(s, 1);
    if (h == 0) atomicAdd(&gap[b * C + c], s);
    __syncthreads();
    const int l = tid & 63, quarter = tid >> 6, cb = quarter * 32;
    union { ushort_t hh[32]; uint4 q[4]; } u;
#pragma unroll
    for (int k = 0; k < 32; k++) u.hh[k] = f2bf(xs[l][cb + k]);
    uint4* dst = (uint4*)(xb + ((size_t)(b * L + l0 + l)) * C + cb);
#pragma unroll
    for (int k = 0; k < 4; k++) dst[k] = u.q[k];
}

// ------------------------------------------------ k_prep_b: gap norm -> a (mlp1 pre-coef), gd0..2 = (g @ Wco) * wcd taps
__global__ __launch_bounds__(128) void k_prep_b(const float* __restrict__ gap,
                                                const float* __restrict__ w1,
                                                const float* __restrict__ Wco,
                                                const float* __restrict__ wcd,
                                                float* __restrict__ a,
                                                float* __restrict__ gd0,
                                                float* __restrict__ gd1,
                                                float* __restrict__ gd2) {
    int b = blockIdx.x, c = threadIdx.x;
    __shared__ float gl[C];
    __shared__ float red[C];
    float v = gap[b * C + c] * (1.f / (float)L);
    red[c] = v * v;
    __syncthreads();
    for (int w = 64; w > 0; w >>= 1) {
        if (c < w) red[c] += red[c + w];
        __syncthreads();
    }
    float nrm = fmaxf(sqrtf(red[0]), 1e-12f);
    float gc = v / nrm;
    gl[c] = gc;
    __syncthreads();
    if (c < MID) {
        float s = 0.f;
        for (int k = 0; k < C; k++) s = fmaf(w1[c * C + k], gl[k], s);
        a[b * MID + c] = s;
    }
    {
        float s = 0.f;
        for (int k = 0; k < C; k++) s = fmaf(gl[k], Wco[k * C + c], s);
        gd0[b * C + c] = s * wcd[3 * c];
        gd1[b * C + c] = s * wcd[3 * c + 1];
        gd2[b * C + c] = s * wcd[3 * c + 2];
    }
}

// ------------------------------------------------ k_prep_w
__global__ __launch_bounds__(128) void k_prep_w(const float* __restrict__ Win,
                                                const float* __restrict__ Wci,
                                                const float* __restrict__ Wproj,
                                                const float* __restrict__ Wout,
                                                const float* __restrict__ w2,
                                                const float* __restrict__ b2,
                                                const float* __restrict__ wds,
                                                ushort_t* __restrict__ Wio,
                                                ushort_t* __restrict__ Wcat,
                                                float* __restrict__ bp,
                                                float* __restrict__ kwS,
                                                float* __restrict__ kw1) {
    int o = blockIdx.x, c = threadIdx.x;
    __shared__ float pr[C];
    pr[c] = Wproj[o * C + c];
    __syncthreads();
    Wio[o * C + c] = f2bf(Win[o * C + c]);
    Wio[(C + o) * C + c] = f2bf(Wci[o * C + c]);
    float s = 0.f;
    for (int k = 0; k < C; k++) s = fmaf(pr[k], Wout[k * C + c], s);
    Wcat[o * 288 + c] = f2bf(s);
    Wcat[o * 288 + 128 + c] = f2bf(pr[c]);
    if (c < MID) {
        float s2 = 0.f;
        for (int k = 0; k < C; k++) s2 = fmaf(pr[k], w2[k * MID + c], s2);
        Wcat[o * 288 + 256 + c] = f2bf(s2);
    }
    if (c == 0) {
        float s3 = 0.f;
        for (int k = 0; k < C; k++) s3 = fmaf(pr[k], b2[k], s3);
        bp[o] = s3;
    }
    if (o == 0) {
        kwS[c] = 0.25f * (wds[3 * c] + wds[3 * c + 2]);
        kw1[c] = wds[3 * c + 1];
    }
}

// ------------------------------------------------ k_gemm1: tu_t[l][0:256] = [Win;Wci] @ x  (MFMA)
__global__ __launch_bounds__(512, 1) void k_gemm1(const ushort_t* __restrict__ xb,
                                                  const ushort_t* __restrict__ Wio,
                                                  ushort_t* __restrict__ tu) {
    __shared__ ushort_t wl[128 * 136];
    const int tid = threadIdx.x;
    const int bid = blockIdx.x;               // 8 b * 2 ms * 128 lt
    const int b = bid >> 8;
    const int ms = (bid >> 7) & 1;
    const int lt = bid & 127;
    {
        int row = tid >> 2, qq = tid & 3;     // 128 rows, 32-ushort chunk each
        const uint4* s4 = (const uint4*)(Wio + (ms * C + row) * C + qq * 32);
        uint4* d4 = (uint4*)(wl + row * 136 + qq * 32);
        d4[0] = s4[0]; d4[1] = s4[1]; d4[2] = s4[2]; d4[3] = s4[3];
    }
    __syncthreads();
    const int wave = tid >> 6, lane = tid & 63;
    const int l0 = lt * 128 + wave * 16;
    const int n = lane & 15, q = lane >> 4;
    const ushort_t* brow = xb + ((size_t)(b * L + l0 + n)) * C + q * 8;
    s8v bfrag[4];
#pragma unroll
    for (int ks = 0; ks < 4; ks++) bfrag[ks] = *(const s8v*)(brow + ks * 32);
    f4v acc[8];
#pragma unroll
    for (int i = 0; i < 8; i++) acc[i] = (f4v){0.f, 0.f, 0.f, 0.f};
#pragma unroll
    for (int ks = 0; ks < 4; ks++) {
#pragma unroll
        for (int mt = 0; mt < 8; mt++) {
            s8v af = *(const s8v*)(wl + (mt * 16 + n) * 136 + ks * 32 + q * 8);
            acc[mt] = __builtin_amdgcn_mfma_f32_16x16x32_bf16(af, bfrag[ks], acc[mt], 0, 0, 0);
        }
    }
    ushort_t* orow = tu + ((size_t)(b * L + l0 + n)) * 256 + ms * C + q * 4;
#pragma unroll
    for (int mt = 0; mt < 8; mt++) {
        union { ushort_t h[4]; uint2 q2; } u;
#pragma unroll
        for (int i = 0; i < 4; i++) u.h[i] = f2bf(acc[mt][i]);
        *(uint2*)(orow + mt * 16) = u.q2;
    }
}

// ------------------------------------------------ k_gemm2f: fused stencil+silu B-frag gen -> GEMM -> out + BN partial stats
// grid: 8 b * 128 y = 1024 blocks, 512 threads (8 waves; wave covers 16 l)
__global__ __launch_bounds__(512, 4) void k_gemm2f(const ushort_t* __restrict__ tu,
                                                   const ushort_t* __restrict__ xb,
                                                   const ushort_t* __restrict__ Wcat,
                                                   const float* __restrict__ kwS,
                                                   const float* __restrict__ kw1,
                                                   const float* __restrict__ gd0,
                                                   const float* __restrict__ gd1,
                                                   const float* __restrict__ gd2,
                                                   const float* __restrict__ a,
                                                   const float* __restrict__ b1,
                                                   const float* __restrict__ pdw,
                                                   const float* __restrict__ bp,
                                                   float* __restrict__ outp,
                                                   float* __restrict__ stats) {
    __shared__ ushort_t wl[128 * 296];        // 75,776 B: full Wcat 128x288 (pad 296)
    const int tid = threadIdx.x;
    const int bid = blockIdx.x;
    const int b = bid >> 7;
    const int y = bid & 127;

    // stage Wcat: 128 rows * 36 uint4 = 4608 uint4; 512 thr * 9
#pragma unroll
    for (int i = 0; i < 9; i++) {
        int idx = tid + i * 512;
        int row = idx / 36, col = idx - row * 36;
        *(uint4*)(wl + row * 296 + col * 8) = *(const uint4*)(Wcat + row * 288 + col * 8);
    }

    const int wave = tid >> 6, lane = tid & 63;
    const int n = lane & 15, q = lane >> 4;
    const int xg = wave * 16 + n;             // x within image row
    const int l = y * 128 + xg;
    const size_t rb = (size_t)b * L;

    // stencil neighbor rows (identical logic to previous k_mid)
    const int rL = (l > 0) ? (l - 1) : -1;
    const int rR = (l < L - 1) ? (l + 1) : -1;
    const int rU = (y > 0) ? (l - 128) : ((xg > 0) ? (16256 + xg - 1) : -1);
    const int rD = (y < 127) ? (l + 128) : ((xg < 127) ? (xg + 1) : -1);
    const int sL = (xg > 0) ? (l - 1) : (l + 1);
    const int sR = (xg < 127) ? (l + 1) : (l - 1);
    const int sU = (y > 0) ? (l - 128) : (l + 128);
    const int sD = (y < 127) ? (l + 128) : (l - 128);

    // ---- s1: per-row dot over u-channels (this lane covers c = q*32 .. q*32+32) ----
    float s1 = 0.f;
    {
        const ushort_t* pC = tu + (rb + l) * 256 + 128 + q * 32;
        const ushort_t* pL = (rL >= 0) ? (tu + (rb + rL) * 256 + 128 + q * 32) : (const ushort_t*)0;
        const ushort_t* pR = (rR >= 0) ? (tu + (rb + rR) * 256 + 128 + q * 32) : (const ushort_t*)0;
#pragma unroll
        for (int j = 0; j < 4; j++) {
            float uC[8], uL8[8], uR8[8], g0[8], g1[8], g2[8];
            load8(pC + j * 8, uC);
            if (pL) load8(pL + j * 8, uL8); else zero8(uL8);
            if (pR) load8(pR + j * 8, uR8); else zero8(uR8);
            const int cb2 = b * C + q * 32 + j * 8;
            ld8f(gd0 + cb2, g0); ld8f(gd1 + cb2, g1); ld8f(gd2 + cb2, g2);
#pragma unroll
            for (int j2 = 0; j2 < 8; j2++) {
                s1 = fmaf(g0[j2], uL8[j2], s1);
                s1 = fmaf(g1[j2], uC[j2], s1);
                s1 = fmaf(g2[j2], uR8[j2], s1);
            }
        }
    }
    s1 += __shfl_xor(s1, 16);
    s1 += __shfl_xor(s1, 32);

    const float dwt = pdw[0] * 0.25f;

    f4v acc[8];
#pragma unroll
    for (int i = 0; i < 8; i++) acc[i] = (f4v){0.f, 0.f, 0.f, 0.f};

    __syncthreads();

    // ---- ks = 0..3 : ct chunks (spatial stencil on t-part of tu) ----
    {
        const ushort_t* ptC = tu + (rb + l) * 256;
        const ushort_t* ptL = (rL >= 0) ? (tu + (rb + rL) * 256) : (const ushort_t*)0;
        const ushort_t* ptR = (rR >= 0) ? (tu + (rb + rR) * 256) : (const ushort_t*)0;
        const ushort_t* ptU = (rU >= 0) ? (tu + (rb + rU) * 256) : (const ushort_t*)0;
        const ushort_t* ptD = (rD >= 0) ? (tu + (rb + rD) * 256) : (const ushort_t*)0;
#pragma unroll
        for (int ks = 0; ks < 4; ks++) {
            const int c0 = ks * 32 + q * 8;
            float tC[8], tLe[8], tRi[8], tUp[8], tDo[8], kS[8], k1[8];
            load8(ptC + c0, tC);
            if (ptL) load8(ptL + c0, tLe); else zero8(tLe);
            if (ptR) load8(ptR + c0, tRi); else zero8(tRi);
            if (ptU) load8(ptU + c0, tUp); else zero8(tUp);
            if (ptD) load8(ptD + c0, tDo); else zero8(tDo);
            ld8f(kwS + c0, kS); ld8f(kw1 + c0, k1);
            union { ushort_t h[8]; s8v v; } bf;
#pragma unroll
            for (int j = 0; j < 8; j++) {
                float ct = kS[j] * ((tLe[j] + tRi[j]) + (tUp[j] + tDo[j])) + k1[j] * tC[j];
                bf.h[j] = f2bf(ct);
            }
#pragma unroll
            for (int mt = 0; mt < 8; mt++) {
                s8v af = *(const s8v*)(wl + (mt * 16 + n) * 296 + ks * 32 + q * 8);
                acc[mt] = __builtin_amdgcn_mfma_f32_16x16x32_bf16(af, bf.v, acc[mt], 0, 0, 0);
            }
        }
    }

    // ---- ks = 4..7 : yd chunks (diff stencil on xb) ----
    {
        const ushort_t* pxC = xb + (rb + l) * C;
        const ushort_t* pxL = xb + (rb + sL) * C;
        const ushort_t* pxR = xb + (rb + sR) * C;
        const ushort_t* pxU = xb + (rb + sU) * C;
        const ushort_t* pxD = xb + (rb + sD) * C;
#pragma unroll
        for (int ks = 0; ks < 4; ks++) {
            const int c0 = ks * 32 + q * 8;
            float xC[8], xL8[8], xR8[8], xU8[8], xD8[8];
            load8(pxC + c0, xC);
            load8(pxL + c0, xL8);
            load8(pxR + c0, xR8);
            load8(pxU + c0, xU8);
            load8(pxD + c0, xD8);
            union { ushort_t h[8]; s8v v; } bf;
#pragma unroll
            for (int j = 0; j < 8; j++) {
                float cen = xC[j];
                float d = fabsf(cen - xL8[j]) + fabsf(cen - xR8[j]) +
                          fabsf(cen - xU8[j]) + fabsf(cen - xD8[j]);
                bf.h[j] = f2bf(fmaf(dwt, d, cen));
            }
#pragma unroll
            for (int mt = 0; mt < 8; mt++) {
                s8v af = *(const s8v*)(wl + (mt * 16 + n) * 296 + (4 + ks) * 32 + q * 8);
                acc[mt] = __builtin_amdgcn_mfma_f32_16x16x32_bf16(af, bf.v, acc[mt], 0, 0, 0);
            }
        }
    }

    // ---- ks = 8 : silu chunk (this lane covers MID cols q*8 .. q*8+8) ----
    {
        float av[8], bv[8];
        ld8f(a + b * MID + q * 8, av);
        ld8f(b1 + q * 8, bv);
        union { ushort_t h[8]; s8v v; } bf;
#pragma unroll
        for (int j = 0; j < 8; j++) {
            float pre = fmaf(av[j], s1, bv[j]);
            bf.h[j] = f2bf(pre / (1.f + __expf(-pre)));
        }
#pragma unroll
        for (int mt = 0; mt < 8; mt++) {
            s8v af = *(const s8v*)(wl + (mt * 16 + n) * 296 + 256 + q * 8);
            acc[mt] = __builtin_amdgcn_mfma_f32_16x16x32_bf16(af, bf.v, acc[mt], 0, 0, 0);
        }
    }

    // ---- epilogue: bias + write out ----
#pragma unroll
    for (int mt = 0; mt < 8; mt++) {
        const int o0 = mt * 16 + q * 4;
        float4 bv4 = *(const float4*)(bp + o0);
        float ba[4] = {bv4.x, bv4.y, bv4.z, bv4.w};
#pragma unroll
        for (int i = 0; i < 4; i++) {
            outp[((size_t)(b * C + o0 + i)) * L + l] = acc[mt][i] + ba[i];
        }
    }

    // ---- BN partial stats: re-read own 128x128 tile (L2-hot) ----
    __syncthreads();
    {
        const int o = tid >> 2, seg = tid & 3;
        const float* pr = outp + ((size_t)(b * C + o)) * L + y * 128 + seg * 32;
        float s = 0.f, sq = 0.f;
#pragma unroll
        for (int i = 0; i < 8; i++) {
            float4 v = *(const float4*)(pr + i * 4);
            s += (v.x + v.y) + (v.z + v.w);
            sq += v.x * v.x + v.y * v.y + v.z * v.z + v.w * v.w;
        }
        s += __shfl_xor(s, 1); sq += __shfl_xor(sq, 1);
        s += __shfl_xor(s, 2); sq += __shfl_xor(sq, 2);
        if (seg == 0) {
            atomicAdd(&stats[o], s);
            atomicAdd(&stats[C + o], sq);
        }
    }
}

// ------------------------------------------------ BN finalize + apply
__global__ void k_bnfin(const float* __restrict__ stats, const float* __restrict__ gamma,
                        const float* __restrict__ beta, float* __restrict__ scsh) {
    int o = threadIdx.x;
    float n = (float)NBL;
    float mu = stats[o] / n;
    float var = stats[C + o] / n - mu * mu;
    float sc = gamma[o] * rsqrtf(var + 1e-5f);
    scsh[o] = sc;
    scsh[C + o] = fmaf(-mu, sc, beta[o]);
}

__global__ __launch_bounds__(256) void k_bnapply(float* __restrict__ outp,
                                                 const float* __restrict__ scsh) {
    int bo = blockIdx.x;
    int o = bo & (C - 1);
    float sc = scsh[o], sh = scsh[C + o];
    float4* p = (float4*)(outp + (size_t)bo * L);
    for (int i = threadIdx.x; i < L / 4; i += 256) {
        float4 v = p[i];
        v.x = fmaf(v.x, sc, sh);
        v.y = fmaf(v.y, sc, sh);
        v.z = fmaf(v.z, sc, sh);
        v.w = fmaf(v.w, sc, sh);
        p[i] = v;
    }
}

// ------------------------------------------------ launch
extern "C" void kernel_launch(void* const* d_in, const int* in_sizes, int n_in,
                              void* d_out, int out_size, void* d_ws, size_t ws_size,
                              hipStream_t stream) {
    const float* x = (const float*)d_in[0];
    const float* Win = (const float*)d_in[1];
    const float* wds = (const float*)d_in[2];
    const float* Wout = (const float*)d_in[3];
    const float* Wci = (const float*)d_in[4];
    const float* wcd = (const float*)d_in[5];
    const float* Wco = (const float*)d_in[6];
    const float* w1 = (const float*)d_in[7];
    const float* b1 = (const float*)d_in[8];
    const float* w2 = (const float*)d_in[9];
    const float* b2 = (const float*)d_in[10];
    const float* pdw = (const float*)d_in[11];
    const float* gamma = (const float*)d_in[12];
    const float* beta = (const float*)d_in[13];
    const float* Wproj = (const float*)d_in[14];

    char* wsb = (char*)d_ws;
    ushort_t* xb = (ushort_t*)wsb;                       // 33,554,432 B
    ushort_t* tu = (ushort_t*)(wsb + 33554432);          // 67,108,864 B
    // former Kb region (now free): use for gd0..2 (B*C fp32 each = 4 KB)
    float* gd0 = (float*)(wsb + 100663296);
    float* gd1 = (float*)(wsb + 100663296 + 4096);
    float* gd2 = (float*)(wsb + 100663296 + 8192);
    char* S = wsb + 176160768;
    float* gap  = (float*)(S + 0);        // 1024
    float* stats= (float*)(S + 4096);     // 256
    float* scsh = (float*)(S + 5120);     // 256
    float* a    = (float*)(S + 6144);     // 256
    float* bp   = (float*)(S + 11264);    // 128
    float* kwS  = (float*)(S + 11776);
    float* kw1  = (float*)(S + 12288);
    ushort_t* Wio  = (ushort_t*)(S + 14336);   // 65,536 B
    ushort_t* Wcat = (ushort_t*)(S + 79872);   // 73,728 B
    float* outp = (float*)d_out;

    hipMemsetAsync(S, 0, 5120, stream);  // gap + stats
    k_cvt<<<2048, 256, 0, stream>>>(x, xb, gap);
    k_prep_b<<<8, 128, 0, stream>>>(gap, w1, Wco, wcd, a, gd0, gd1, gd2);
    k_prep_w<<<128, 128, 0, stream>>>(Win, Wci, Wproj, Wout, w2, b2, wds,
                                      Wio, Wcat, bp, kwS, kw1);
    k_gemm1<<<2048, 512, 0, stream>>>(xb, Wio, tu);
    k_gemm2f<<<1024, 512, 0, stream>>>(tu, xb, Wcat, kwS, kw1, gd0, gd1, gd2,
                                       a, b1, pdw, bp, outp, stats);
    k_bnfin<<<1, 128, 0, stream>>>(stats, gamma, beta, scsh);
    k_bnapply<<<1024, 256, 0, stream>>>(outp, scsh);
}